// Round 5
// baseline (2146.825 us; speedup 1.0000x reference)
//
#include <hip/hip_runtime.h>
#include <stdint.h>

#define TOKENS 8192
#define IN_F   4096
#define OUT_F  4096

#define BM 256
#define BN 256
#define BK 64                 // bytes of K per slice (64 int8)
#define NK (IN_F / BK)        // 64 slices
#define THREADS 1024

typedef int v4i __attribute__((ext_vector_type(4)));

#define GLOBAL_AS __attribute__((address_space(1)))
#define LDS_AS    __attribute__((address_space(3)))

// ---------------- pack x: int32 -> int8 ----------------
__global__ __launch_bounds__(256) void pack_x_kernel(const int* __restrict__ x32,
                                                     uint8_t* __restrict__ x8) {
  int t = blockIdx.x * 256 + threadIdx.x;
  const int4 v = ((const int4*)x32)[t];
  uint32_t p = (uint32_t)(v.x & 0xFF)
             | ((uint32_t)(v.y & 0xFF) << 8)
             | ((uint32_t)(v.z & 0xFF) << 16)
             | ((uint32_t)(v.w & 0xFF) << 24);
  ((uint32_t*)x8)[t] = p;
}

// -------- pack + transpose W: int32 [K][N] -> int8 WT [N][K] --------
__global__ __launch_bounds__(256) void packT_w_kernel(const int* __restrict__ w32,
                                                      uint8_t* __restrict__ wt8) {
  int tn = (blockIdx.x & 63) * 64;
  int tk = (blockIdx.x >> 6) * 64;
  int t = threadIdx.x;
  int n  = tn + (t >> 2);
  int k0 = tk + (t & 3) * 16;
  uint32_t words[4];
#pragma unroll
  for (int w = 0; w < 4; ++w) {
    uint32_t acc = 0;
#pragma unroll
    for (int j = 0; j < 4; ++j) {
      int val = w32[(size_t)(k0 + w * 4 + j) * OUT_F + n];
      acc |= (uint32_t)(val & 0xFF) << (8 * j);
    }
    words[w] = acc;
  }
  uint4 o = make_uint4(words[0], words[1], words[2], words[3]);
  *(uint4*)(wt8 + (size_t)n * IN_F + k0) = o;
}

// ---------------- int8 GEMM: 256x256, 1024 thr, ring-2, 2 blocks/CU ----------------
// 16 waves (4m x 4n), wave tile 64x64, 4x4 frags of mfma_i32_16x16x64_i8 (acc 64 VGPR).
// Ring: 2 slots x 32 KiB (A slice 16 KiB @0, B slice 16 KiB @16384) = 64 KiB ->
// 2 blocks/CU; cross-block wave overlap covers intra-block barrier/lgkm stalls.
__global__ __launch_bounds__(THREADS, 8) void gemm_i8_kernel(const uint8_t* __restrict__ A,
                                                             const uint8_t* __restrict__ BT,
                                                             const int* __restrict__ bias,
                                                             const float* __restrict__ scales,
                                                             int* __restrict__ out) {
  __shared__ __align__(16) uint8_t lds[2 * 32768];   // 64 KiB

  const int t    = threadIdx.x;
  const int lane = t & 63;
  const int w    = t >> 6;     // 0..15
  const int wm   = w >> 2;     // 0..3
  const int wn   = w & 3;      // 0..3
  const int fr   = lane & 15;
  const int fq   = lane >> 4;

  // XCD-aware bijective swizzle: 512 blocks, 512 % 8 == 0
  int bid = blockIdx.x;
  int swz = (bid & 7) * 64 + (bid >> 3);
  int bm = swz >> 4;           // 0..31
  int bn = swz & 15;           // 0..15

  // staging: pre-swizzled global source, linear LDS dest (rule #21).
  // sigma(l) = l ^ ((l>>3)&7) on 16B chunks (involution; verified 0-conflict R3/R4)
  const int lsz  = t ^ ((t >> 3) & 7);
  const int srow = lsz >> 2;            // 0..255
  const int scol = (lsz & 3) * 16;
  const size_t gA = (size_t)(bm * BM + srow) * IN_F + scol;
  const size_t gB = (size_t)(bn * BN + srow) * IN_F + scol;
  const int ldst = t * 16;              // 0..16383 linear within 16 KiB region

  auto stage = [&](int j) {
    uint8_t* sb = lds + (j & 1) * 32768;
    const int k0 = j * BK;
    __builtin_amdgcn_global_load_lds((const GLOBAL_AS void*)(A  + gA + k0),
                                     (LDS_AS void*)(sb + ldst),          16, 0, 0);
    __builtin_amdgcn_global_load_lds((const GLOBAL_AS void*)(BT + gB + k0),
                                     (LDS_AS void*)(sb + 16384 + ldst),  16, 0, 0);
  };

  // fragment read offsets (slot-relative), sigma-swizzled to match staging
  int aoff[4], boff[4];
#pragma unroll
  for (int m = 0; m < 4; ++m) {
    int row = wm * 64 + m * 16 + fr;        // 0..255
    int b = row * 64 + fq * 16;
    b ^= ((row >> 1) & 7) << 4;
    aoff[m] = b;
  }
#pragma unroll
  for (int n = 0; n < 4; ++n) {
    int row = wn * 64 + n * 16 + fr;        // 0..255
    int b = row * 64 + fq * 16;
    b ^= ((row >> 1) & 7) << 4;
    boff[n] = 16384 + b;
  }

  v4i acc[4][4];
  const v4i vzero = {0, 0, 0, 0};
#pragma unroll
  for (int m = 0; m < 4; ++m)
#pragma unroll
    for (int n = 0; n < 4; ++n) acc[m][n] = vzero;

  stage(0);

  // Iter i: stage(i+1) [slot free: its readers drained before iter i-1's
  // trailing barrier]; vmcnt(2) -> slice i's 2 loads landed (i+1's still in
  // flight -- never drain to 0 mid-loop); barrier; ds_read; lgkm0; 16 MFMA; barrier.
#define ITER(i, VM, DOSTAGE)                                                    \
  {                                                                             \
    if (DOSTAGE) stage((i) + 1);                                                \
    asm volatile("s_waitcnt vmcnt(" #VM ")" ::: "memory");                      \
    asm volatile("s_barrier" ::: "memory");                                     \
    const uint8_t* sb = lds + ((i) & 1) * 32768;                                \
    v4i af[4], bf[4];                                                           \
    _Pragma("unroll") for (int m = 0; m < 4; ++m)                               \
      af[m] = *(const v4i*)(sb + aoff[m]);                                      \
    _Pragma("unroll") for (int n = 0; n < 4; ++n)                               \
      bf[n] = *(const v4i*)(sb + boff[n]);                                      \
    asm volatile("s_waitcnt lgkmcnt(0)" ::: "memory");                          \
    __builtin_amdgcn_sched_barrier(0);                                          \
    __builtin_amdgcn_s_setprio(1);                                              \
    _Pragma("unroll") for (int m = 0; m < 4; ++m)                               \
      _Pragma("unroll") for (int n = 0; n < 4; ++n)                             \
        acc[m][n] = __builtin_amdgcn_mfma_i32_16x16x64_i8(af[m], bf[n],         \
                                                          acc[m][n], 0, 0, 0);  \
    __builtin_amdgcn_s_setprio(0);                                              \
    asm volatile("s_barrier" ::: "memory");                                     \
  }

  for (int i = 0; i < NK - 1; ++i) {
    ITER(i, 2, true)
  }
  ITER(NK - 1, 0, false)
#undef ITER

  // ---- epilogue: (acc + bias) * scale * 20, clip, trunc; int32 out ----
  // C/D layout (16x16): col = lane&15, row = (lane>>4)*4 + r
#pragma unroll
  for (int n = 0; n < 4; ++n) {
    const int gn  = bn * BN + wn * 64 + n * 16 + fr;
    const int bsv = bias[gn];
    const float sc = scales[gn] * 20.0f;
#pragma unroll
    for (int m = 0; m < 4; ++m) {
      const int gm0 = bm * BM + wm * 64 + m * 16 + fq * 4;
#pragma unroll
      for (int r = 0; r < 4; ++r) {
        float g = (float)(acc[m][n][r] + bsv) * sc;
        g = fminf(fmaxf(g, -128.0f), 127.0f);
        out[(size_t)(gm0 + r) * OUT_F + gn] = (int)g;
      }
    }
  }
}

extern "C" void kernel_launch(void* const* d_in, const int* in_sizes, int n_in,
                              void* d_out, int out_size, void* d_ws, size_t ws_size,
                              hipStream_t stream) {
  const int*   x32    = (const int*)d_in[0];
  const int*   w32    = (const int*)d_in[1];
  const int*   bias   = (const int*)d_in[2];
  const float* scales = (const float*)d_in[3];
  int* out = (int*)d_out;

  uint8_t* x8  = (uint8_t*)d_ws;                              // 32 MB
  uint8_t* wt8 = (uint8_t*)d_ws + (size_t)TOKENS * IN_F;      // 16 MB

  pack_x_kernel<<<(TOKENS * IN_F / 4) / 256, 256, 0, stream>>>(x32, x8);
  packT_w_kernel<<<(OUT_F / 64) * (IN_F / 64), 256, 0, stream>>>(w32, wt8);
  gemm_i8_kernel<<<(TOKENS / BM) * (OUT_F / BN), THREADS, 0, stream>>>(x8, wt8, bias, scales, out);
}

// Round 7
// 189.725 us; speedup vs baseline: 11.3155x; 11.3155x over previous
//
#include <hip/hip_runtime.h>
#include <stdint.h>

#define TOKENS 8192
#define IN_F   4096
#define OUT_F  4096

#define BM 256
#define BN 256
#define BK 64                 // bytes of K per slice (64 int8)
#define NK (IN_F / BK)        // 64 slices
#define THREADS 512

typedef int v4i __attribute__((ext_vector_type(4)));

#define GLOBAL_AS __attribute__((address_space(1)))
#define LDS_AS    __attribute__((address_space(3)))

// ---------------- pack x: int32 -> int8 ----------------
__global__ __launch_bounds__(256) void pack_x_kernel(const int* __restrict__ x32,
                                                     uint8_t* __restrict__ x8) {
  int t = blockIdx.x * 256 + threadIdx.x;
  const int4 v = ((const int4*)x32)[t];
  uint32_t p = (uint32_t)(v.x & 0xFF)
             | ((uint32_t)(v.y & 0xFF) << 8)
             | ((uint32_t)(v.z & 0xFF) << 16)
             | ((uint32_t)(v.w & 0xFF) << 24);
  ((uint32_t*)x8)[t] = p;
}

// -------- pack + transpose W: int32 [K][N] -> int8 WT [N][K] --------
__global__ __launch_bounds__(256) void packT_w_kernel(const int* __restrict__ w32,
                                                      uint8_t* __restrict__ wt8) {
  int tn = (blockIdx.x & 63) * 64;
  int tk = (blockIdx.x >> 6) * 64;
  int t = threadIdx.x;
  int n  = tn + (t >> 2);
  int k0 = tk + (t & 3) * 16;
  uint32_t words[4];
#pragma unroll
  for (int w = 0; w < 4; ++w) {
    uint32_t acc = 0;
#pragma unroll
    for (int j = 0; j < 4; ++j) {
      int val = w32[(size_t)(k0 + w * 4 + j) * OUT_F + n];
      acc |= (uint32_t)(val & 0xFF) << (8 * j);
    }
    words[w] = acc;
  }
  uint4 o = make_uint4(words[0], words[1], words[2], words[3]);
  *(uint4*)(wt8 + (size_t)n * IN_F + k0) = o;
}

// ---------------- int8 GEMM: 256x256, ring-4, read-ahead pipeline ----------------
// 8 waves (2m x 4n), wave tile 128x64, 8x4 frags of mfma_i32_16x16x64_i8.
// Per slice: one barrier; issue af2(i)+bf/af(i+1) ds_reads + stage(i+3) up
// front; cluster1 runs on regs read LAST slice (no wait); counted auto-lgkm
// lets af2 land under cluster1 and next-slice frags under cluster2.
__global__ __launch_bounds__(THREADS, 2) void gemm_i8_kernel(const uint8_t* __restrict__ A,
                                                             const uint8_t* __restrict__ BT,
                                                             const int* __restrict__ bias,
                                                             const float* __restrict__ scales,
                                                             int* __restrict__ out) {
  __shared__ __align__(16) uint8_t lds[4 * 32768];   // 128 KiB, ring of 4 slices

  const int t    = threadIdx.x;
  const int lane = t & 63;
  const int w    = t >> 6;
  const int wr   = w >> 2;     // 0..1
  const int wc   = w & 3;      // 0..3
  const int fr   = lane & 15;
  const int fq   = lane >> 4;

  // XCD-aware bijective swizzle: 512 blocks, 512 % 8 == 0
  int bid = blockIdx.x;
  int swz = (bid & 7) * 64 + (bid >> 3);
  int bm = swz >> 4;           // 0..31
  int bn = swz & 15;           // 0..15

  // staging: pre-swizzled global source, linear LDS dest (rule #21).
  // sigma(l) = l ^ ((l>>3)&7) on 16B chunks (verified 0-conflict R3/R4)
  const int lsz  = t ^ ((t >> 3) & 7);
  const int srow = lsz >> 2;
  const int scol = (lsz & 3) * 16;
  const size_t gA0 = (size_t)(bm * BM + srow) * IN_F + scol;
  const size_t gA1 = gA0 + (size_t)128 * IN_F;
  const size_t gB0 = (size_t)(bn * BN + srow) * IN_F + scol;
  const size_t gB1 = gB0 + (size_t)128 * IN_F;
  const int ldst = t * 16;

  auto stage = [&](int j) {
    uint8_t* sb = lds + (j & 3) * 32768;
    const int k0 = j * BK;
    __builtin_amdgcn_global_load_lds((const GLOBAL_AS void*)(A + gA0 + k0),
                                     (LDS_AS void*)(sb + ldst),          16, 0, 0);
    __builtin_amdgcn_global_load_lds((const GLOBAL_AS void*)(A + gA1 + k0),
                                     (LDS_AS void*)(sb + 8192 + ldst),   16, 0, 0);
    __builtin_amdgcn_global_load_lds((const GLOBAL_AS void*)(BT + gB0 + k0),
                                     (LDS_AS void*)(sb + 16384 + ldst),  16, 0, 0);
    __builtin_amdgcn_global_load_lds((const GLOBAL_AS void*)(BT + gB1 + k0),
                                     (LDS_AS void*)(sb + 24576 + ldst),  16, 0, 0);
  };

  // fragment read offsets (slot-relative), sigma-swizzled to match staging
  int aoff[8], boff[4];
#pragma unroll
  for (int m = 0; m < 8; ++m) {
    int row = wr * 128 + m * 16 + fr;
    int half = row >> 7, rl = row & 127;
    int b = rl * 64 + fq * 16;
    b ^= ((rl >> 1) & 7) << 4;
    aoff[m] = half * 8192 + b;
  }
#pragma unroll
  for (int n = 0; n < 4; ++n) {
    int row = wc * 64 + n * 16 + fr;
    int half = row >> 7, rl = row & 127;
    int b = rl * 64 + fq * 16;
    b ^= ((rl >> 1) & 7) << 4;
    boff[n] = 16384 + half * 8192 + b;
  }

  v4i acc[8][4];
  const v4i vzero = {0, 0, 0, 0};
#pragma unroll
  for (int m = 0; m < 8; ++m)
#pragma unroll
    for (int n = 0; n < 4; ++n) acc[m][n] = vzero;

  // BODY(i): vmcnt(VM); barrier; issue af2(i) + [bf/af(i+1)] + [stage(i+3)];
  // cluster1(i) on afCUR/bfCUR (no wait); cluster2(i) on af2 (auto counted lgkm).
  // Hazards: stage targets slot (i-1)&3 whose last reads (af2(i-1)) drained
  // before this barrier; slot (i+1)&3 hoisted reads drain one barrier before
  // its re-stage at slice i+2. vmcnt(4) at head: slots i, i+1 landed, only
  // stage(i+2)'s 4 loads in flight (never drains to 0 mid-loop).
#define BODY(i, VM, DOSTAGE, DONEXT, afCUR, bfCUR, afNXT, bfNXT)                \
  {                                                                             \
    asm volatile("s_waitcnt vmcnt(" #VM ")" ::: "memory");                      \
    asm volatile("s_barrier" ::: "memory");                                     \
    const uint8_t* sb  = lds + ((i) & 3) * 32768;                               \
    const uint8_t* sbn = lds + (((i) + 1) & 3) * 32768;                         \
    v4i af2[4];                                                                 \
    _Pragma("unroll") for (int m = 0; m < 4; ++m)                               \
      af2[m] = *(const v4i*)(sb + aoff[4 + m]);                                 \
    if (DONEXT) {                                                               \
      _Pragma("unroll") for (int n = 0; n < 4; ++n)                             \
        bfNXT[n] = *(const v4i*)(sbn + boff[n]);                                \
      _Pragma("unroll") for (int m = 0; m < 4; ++m)                             \
        afNXT[m] = *(const v4i*)(sbn + aoff[m]);                                \
    }                                                                           \
    if (DOSTAGE) stage((i) + 3);                                                \
    __builtin_amdgcn_sched_barrier(0);                                          \
    __builtin_amdgcn_s_setprio(1);                                              \
    _Pragma("unroll") for (int m = 0; m < 4; ++m)                               \
      _Pragma("unroll") for (int n = 0; n < 4; ++n)                             \
        acc[m][n] = __builtin_amdgcn_mfma_i32_16x16x64_i8(afCUR[m], bfCUR[n],   \
                                                          acc[m][n], 0, 0, 0);  \
    __builtin_amdgcn_s_setprio(0);                                              \
    __builtin_amdgcn_s_setprio(1);                                              \
    _Pragma("unroll") for (int m = 0; m < 4; ++m)                               \
      _Pragma("unroll") for (int n = 0; n < 4; ++n)                             \
        acc[4 + m][n] = __builtin_amdgcn_mfma_i32_16x16x64_i8(af2[m], bfCUR[n], \
                                                      acc[4 + m][n], 0, 0, 0);  \
    __builtin_amdgcn_s_setprio(0);                                              \
  }

  // Prologue: fill 3 slots. vmcnt(8) drains THIS wave's slot-0 loads; the
  // s_barrier then makes EVERY wave's slot-0 writes visible before the
  // preload reads (R6's missing sync — reads raced other waves' staging).
  stage(0); stage(1); stage(2);
  asm volatile("s_waitcnt vmcnt(8)" ::: "memory");   // own slot-0 loads landed
  asm volatile("s_barrier" ::: "memory");            // all waves' slot-0 landed
  v4i afC[4], bfC[4], afN[4], bfN[4];
#pragma unroll
  for (int n = 0; n < 4; ++n) bfC[n] = *(const v4i*)(lds + boff[n]);
#pragma unroll
  for (int m = 0; m < 4; ++m) afC[m] = *(const v4i*)(lds + aoff[m]);

  for (int i = 0; i < 60; i += 2) {
    BODY(i,     4, true,  true,  afC, bfC, afN, bfN)
    BODY(i + 1, 4, true,  true,  afN, bfN, afC, bfC)
  }
  BODY(60, 4, true,  true,  afC, bfC, afN, bfN)   // last stage: slot 63
  BODY(61, 4, false, true,  afN, bfN, afC, bfC)
  BODY(62, 0, false, true,  afC, bfC, afN, bfN)
  BODY(63, 0, false, false, afN, bfN, afC, bfC)
#undef BODY

  // ---- epilogue: (acc + bias) * scale * 20, clip, trunc; int32 out ----
  // C/D layout (16x16): col = lane&15, row = (lane>>4)*4 + r
#pragma unroll
  for (int n = 0; n < 4; ++n) {
    const int gn  = bn * BN + wc * 64 + n * 16 + fr;
    const int bsv = bias[gn];
    const float sc = scales[gn] * 20.0f;
#pragma unroll
    for (int m = 0; m < 8; ++m) {
      const int gm0 = bm * BM + wr * 128 + m * 16 + fq * 4;
#pragma unroll
      for (int r = 0; r < 4; ++r) {
        float g = (float)(acc[m][n][r] + bsv) * sc;
        g = fminf(fmaxf(g, -128.0f), 127.0f);
        out[(size_t)(gm0 + r) * OUT_F + gn] = (int)g;
      }
    }
  }
}

extern "C" void kernel_launch(void* const* d_in, const int* in_sizes, int n_in,
                              void* d_out, int out_size, void* d_ws, size_t ws_size,
                              hipStream_t stream) {
  const int*   x32    = (const int*)d_in[0];
  const int*   w32    = (const int*)d_in[1];
  const int*   bias   = (const int*)d_in[2];
  const float* scales = (const float*)d_in[3];
  int* out = (int*)d_out;

  uint8_t* x8  = (uint8_t*)d_ws;                              // 32 MB
  uint8_t* wt8 = (uint8_t*)d_ws + (size_t)TOKENS * IN_F;      // 16 MB

  pack_x_kernel<<<(TOKENS * IN_F / 4) / 256, 256, 0, stream>>>(x32, x8);
  packT_w_kernel<<<(OUT_F / 64) * (IN_F / 64), 256, 0, stream>>>(w32, wt8);
  gemm_i8_kernel<<<(TOKENS / BM) * (OUT_F / BN), THREADS, 0, stream>>>(x8, wt8, bias, scales, out);
}

// Round 8
// 187.229 us; speedup vs baseline: 11.4663x; 1.0133x over previous
//
#include <hip/hip_runtime.h>
#include <stdint.h>

#define TOKENS 8192
#define IN_F   4096
#define OUT_F  4096

#define BM 256
#define BN 256
#define BK 64                 // bytes of K per slice (64 int8)
#define NK (IN_F / BK)        // 64 slices
#define THREADS 1024

typedef int v4i __attribute__((ext_vector_type(4)));

#define GLOBAL_AS __attribute__((address_space(1)))
#define LDS_AS    __attribute__((address_space(3)))

// ---------------- pack x: int32 -> int8 ----------------
__global__ __launch_bounds__(256) void pack_x_kernel(const int* __restrict__ x32,
                                                     uint8_t* __restrict__ x8) {
  int t = blockIdx.x * 256 + threadIdx.x;
  const int4 v = ((const int4*)x32)[t];
  uint32_t p = (uint32_t)(v.x & 0xFF)
             | ((uint32_t)(v.y & 0xFF) << 8)
             | ((uint32_t)(v.z & 0xFF) << 16)
             | ((uint32_t)(v.w & 0xFF) << 24);
  ((uint32_t*)x8)[t] = p;
}

// -------- pack + transpose W: int32 [K][N] -> int8 WT [N][K] --------
__global__ __launch_bounds__(256) void packT_w_kernel(const int* __restrict__ w32,
                                                      uint8_t* __restrict__ wt8) {
  int tn = (blockIdx.x & 63) * 64;
  int tk = (blockIdx.x >> 6) * 64;
  int t = threadIdx.x;
  int n  = tn + (t >> 2);
  int k0 = tk + (t & 3) * 16;
  uint32_t words[4];
#pragma unroll
  for (int w = 0; w < 4; ++w) {
    uint32_t acc = 0;
#pragma unroll
    for (int j = 0; j < 4; ++j) {
      int val = w32[(size_t)(k0 + w * 4 + j) * OUT_F + n];
      acc |= (uint32_t)(val & 0xFF) << (8 * j);
    }
    words[w] = acc;
  }
  uint4 o = make_uint4(words[0], words[1], words[2], words[3]);
  *(uint4*)(wt8 + (size_t)n * IN_F + k0) = o;
}

// ---------------- int8 GEMM: 256x256, 16 waves, ring-4, 4 waves/SIMD ----------------
// 16 waves (4m x 4n), wave tile 64x64, 4x4 frags of mfma_i32_16x16x64_i8 (acc 64 reg).
// cap 128 regs/wave via __launch_bounds__(1024,4): acc 64 + ~50 live -> no spill.
__global__ __launch_bounds__(THREADS, 4) void gemm_i8_kernel(const uint8_t* __restrict__ A,
                                                             const uint8_t* __restrict__ BT,
                                                             const int* __restrict__ bias,
                                                             const float* __restrict__ scales,
                                                             int* __restrict__ out) {
  __shared__ __align__(16) uint8_t lds[4 * 32768];   // ring of 4 slices, 128 KiB

  const int t    = threadIdx.x;
  const int lane = t & 63;
  const int w    = t >> 6;     // 0..15
  const int wm   = w >> 2;     // 0..3
  const int wn   = w & 3;      // 0..3
  const int fr   = lane & 15;
  const int fq   = lane >> 4;

  // XCD-aware bijective swizzle: 512 blocks, 512 % 8 == 0
  int bid = blockIdx.x;
  int swz = (bid & 7) * 64 + (bid >> 3);
  int bm = swz >> 4;           // 0..31
  int bn = swz & 15;           // 0..15

  // staging: pre-swizzled global source, linear LDS dest (rule #21).
  // Per-half (128 rows x 64 B = 8 KiB) layout IDENTICAL to R4/R7 (verified
  // 0-conflict): within half, thread tt writes chunk tt at sigma'd source.
  const int half = t >> 9;              // 0..1: which 128-row half
  const int tt   = t & 511;
  const int lsz  = tt ^ ((tt >> 3) & 7);
  const int srow = half * 128 + (lsz >> 2);   // 0..255
  const int scol = (lsz & 3) * 16;
  const size_t gA = (size_t)(bm * BM + srow) * IN_F + scol;
  const size_t gB = (size_t)(bn * BN + srow) * IN_F + scol;
  const int ldst = half * 8192 + tt * 16;     // linear within 16 KiB region

  auto stage = [&](int j) {            // 2 loads per thread per slice
    uint8_t* sb = lds + (j & 3) * 32768;
    const int k0 = j * BK;
    __builtin_amdgcn_global_load_lds((const GLOBAL_AS void*)(A + gA + k0),
                                     (LDS_AS void*)(sb + ldst),          16, 0, 0);
    __builtin_amdgcn_global_load_lds((const GLOBAL_AS void*)(BT + gB + k0),
                                     (LDS_AS void*)(sb + 16384 + ldst),  16, 0, 0);
  };

  // fragment read offsets (slot-relative), sigma-swizzled to match staging
  int aoff[4], boff[4];
#pragma unroll
  for (int m = 0; m < 4; ++m) {
    int row = wm * 64 + m * 16 + fr;        // 0..255
    int hh = row >> 7, rl = row & 127;
    int b = rl * 64 + fq * 16;
    b ^= ((rl >> 1) & 7) << 4;
    aoff[m] = hh * 8192 + b;
  }
#pragma unroll
  for (int n = 0; n < 4; ++n) {
    int row = wn * 64 + n * 16 + fr;        // 0..255
    int hh = row >> 7, rl = row & 127;
    int b = rl * 64 + fq * 16;
    b ^= ((rl >> 1) & 7) << 4;
    boff[n] = 16384 + hh * 8192 + b;
  }

  v4i acc[4][4];
  const v4i vzero = {0, 0, 0, 0};
#pragma unroll
  for (int m = 0; m < 4; ++m)
#pragma unroll
    for (int n = 0; n < 4; ++n) acc[m][n] = vzero;

  // Prologue: fill 3 slots (6 loads/thread in flight).
  stage(0); stage(1); stage(2);

  // ITER(i): vmcnt(VM) -> slice i landed (i+1,i+2 in flight: never 0 mid-loop);
  // barrier (all waves' writes visible); stage(i+3) -> slot (i-1)&3, whose
  // readers drained at ITER(i-1)'s lgkm0, before this barrier; ds_read 8x b128;
  // lgkm0; 16 MFMA.
#define ITER(i, VM, DOSTAGE)                                                    \
  {                                                                             \
    asm volatile("s_waitcnt vmcnt(" #VM ")" ::: "memory");                      \
    asm volatile("s_barrier" ::: "memory");                                     \
    if (DOSTAGE) stage((i) + 3);                                                \
    const uint8_t* sb = lds + ((i) & 3) * 32768;                                \
    v4i af[4], bf[4];                                                           \
    _Pragma("unroll") for (int m = 0; m < 4; ++m)                               \
      af[m] = *(const v4i*)(sb + aoff[m]);                                      \
    _Pragma("unroll") for (int n = 0; n < 4; ++n)                               \
      bf[n] = *(const v4i*)(sb + boff[n]);                                      \
    asm volatile("s_waitcnt lgkmcnt(0)" ::: "memory");                          \
    __builtin_amdgcn_sched_barrier(0);                                          \
    __builtin_amdgcn_s_setprio(1);                                              \
    _Pragma("unroll") for (int m = 0; m < 4; ++m)                               \
      _Pragma("unroll") for (int n = 0; n < 4; ++n)                             \
        acc[m][n] = __builtin_amdgcn_mfma_i32_16x16x64_i8(af[m], bf[n],         \
                                                          acc[m][n], 0, 0, 0);  \
    __builtin_amdgcn_s_setprio(0);                                              \
  }

  for (int i = 0; i < NK - 3; ++i) {
    ITER(i, 4, true)
  }
  ITER(NK - 3, 4, false)
  ITER(NK - 2, 2, false)
  ITER(NK - 1, 0, false)
#undef ITER

  // ---- epilogue: (acc + bias) * scale * 20, clip, trunc; int32 out ----
  // C/D layout (16x16): col = lane&15, row = (lane>>4)*4 + r
#pragma unroll
  for (int n = 0; n < 4; ++n) {
    const int gn  = bn * BN + wn * 64 + n * 16 + fr;
    const int bsv = bias[gn];
    const float sc = scales[gn] * 20.0f;
#pragma unroll
    for (int m = 0; m < 4; ++m) {
      const int gm0 = bm * BM + wm * 64 + m * 16 + fq * 4;
#pragma unroll
      for (int r = 0; r < 4; ++r) {
        float g = (float)(acc[m][n][r] + bsv) * sc;
        g = fminf(fmaxf(g, -128.0f), 127.0f);
        out[(size_t)(gm0 + r) * OUT_F + gn] = (int)g;
      }
    }
  }
}

extern "C" void kernel_launch(void* const* d_in, const int* in_sizes, int n_in,
                              void* d_out, int out_size, void* d_ws, size_t ws_size,
                              hipStream_t stream) {
  const int*   x32    = (const int*)d_in[0];
  const int*   w32    = (const int*)d_in[1];
  const int*   bias   = (const int*)d_in[2];
  const float* scales = (const float*)d_in[3];
  int* out = (int*)d_out;

  uint8_t* x8  = (uint8_t*)d_ws;                              // 32 MB
  uint8_t* wt8 = (uint8_t*)d_ws + (size_t)TOKENS * IN_F;      // 16 MB

  pack_x_kernel<<<(TOKENS * IN_F / 4) / 256, 256, 0, stream>>>(x32, x8);
  packT_w_kernel<<<(OUT_F / 64) * (IN_F / 64), 256, 0, stream>>>(w32, wt8);
  gemm_i8_kernel<<<(TOKENS / BM) * (OUT_F / BN), THREADS, 0, stream>>>(x8, wt8, bias, scales, out);
}